// Round 12
// baseline (88.395 us; speedup 1.0000x reference)
//
#include <hip/hip_runtime.h>
#include <hip/hip_bf16.h>
#include <hip/hip_fp16.h>

#define NN 50000
#define NE 800000
#define EPS 1e-5f
#define NW 782            // ceil(NN/64) windows of 64 nodes
#define CAP 2560          // fixed per-window colw slots (max window load ~1150)
#define WFB 200           // wfill blocks
#define CHUNK (NE / WFB)  // 4000 edges per wfill block
#define PREPB 64          // prep blocks
#define INPB ((NN + 31) / 32)
#define NSLICE ((NW + 7) / 8)   // 98 prefetch slices per XCD

typedef _Float16 f16;
typedef _Float16 f16x8 __attribute__((ext_vector_type(8)));
typedef float f32x4 __attribute__((ext_vector_type(4)));

__device__ __forceinline__ int waveInclScan(int v, int lane) {
#pragma unroll
    for (int o = 1; o < 64; o <<= 1) {
        int t = __shfl_up(v, o, 64);
        if (lane >= o) v += t;
    }
    return v;
}

// stream a per-XCD slice of [buf, buf+total16) (16B units) into this XCD's L2.
// blocks round-robin XCDs by blockIdx (mod 8); blocks with same residue cover the
// range collectively via slice = wb>>3.
__device__ __forceinline__ void l2_warm(const uint4* __restrict__ buf, int total16,
                                        int wb, int tid, int nthreads) {
    int per = (total16 + NSLICE - 1) / NSLICE;
    int lo = (wb >> 3) * per;
    int hi = lo + per;
    if (hi > total16) hi = total16;
    unsigned acc = 0;
    for (int i = lo + tid; i < hi; i += nthreads) {
        uint4 v = buf[i];
        acc ^= v.x ^ v.y ^ v.z ^ v.w;
    }
    asm volatile("" :: "v"(acc));   // keep loads live (rule #17)
}

// ---------------- prep: weight transposes + wcur init ----------------
__global__ __launch_bounds__(256) void k_prep_init(const float* __restrict__ Win,
                                                   const float* __restrict__ Wl,
                                                   const float* __restrict__ Wr,
                                                   const float* __restrict__ Wl2,
                                                   const float* __restrict__ Wr2,
                                                   const float* __restrict__ Wo1,
                                                   f16* __restrict__ WinT,
                                                   f16* __restrict__ W2T,
                                                   f16* __restrict__ W3T,
                                                   f16* __restrict__ Wo1T,
                                                   int* __restrict__ wcur) {
    int i0 = blockIdx.x * 256 + threadIdx.x;
    for (int i = i0; i < 128 * 104; i += PREPB * 256) {
        int c = i / 104, k = i - c * 104;
        float v = (k < 84) ? Win[k * 128 + c] : 0.f;
        WinT[c * 104 + k] = (f16)v;
    }
    for (int i = i0; i < 128 * 136; i += PREPB * 256) {
        int c = i / 136, k = i - c * 136;
        float v = 0.f;
        if (k < 128) v = (c < 64) ? Wl[k * 64 + c] : Wr[k * 64 + (c - 64)];
        W2T[c * 136 + k] = (f16)v;
    }
    for (int i = i0; i < 64 * 72; i += PREPB * 256) {
        int c = i / 72, k = i - c * 72;
        float v = 0.f;
        if (k < 64) v = (c < 32) ? Wl2[k * 32 + c] : Wr2[k * 32 + (c - 32)];
        W3T[c * 72 + k] = (f16)v;
    }
    for (int i = i0; i < 16 * 40; i += PREPB * 256) {
        int c = i / 40, k = i - c * 40;
        float v = (k < 32) ? Wo1[k * 16 + c] : 0.f;
        Wo1T[c * 40 + k] = (f16)v;
    }
    for (int i = i0; i < NW; i += PREPB * 256) wcur[i] = i * CAP;
}

// ---------------- fused: wfill (blocks <WFB) | MFMA in_proj1 (rest) ----------------
__global__ __launch_bounds__(256) void k_wfill_inproj(const int* __restrict__ src,
                                                      const int* __restrict__ tgt,
                                                      int* __restrict__ wcur,
                                                      int* __restrict__ colw,
                                                      const float* __restrict__ x,
                                                      const f16* __restrict__ WinT,
                                                      const float* __restrict__ bin,
                                                      const f16* __restrict__ W2T,
                                                      const float* __restrict__ bl,
                                                      f16* __restrict__ p1h,
                                                      f16* __restrict__ r1h, int N) {
    __shared__ int lh[NW];
    __shared__ int sb[NW];
    __shared__ __align__(16) f16 xs[32 * 104];
    __shared__ __align__(16) f16 hs[32 * 136];
    int tid = threadIdx.x;

    if (blockIdx.x < WFB) {
        // span-reserved window partition into CAP-strided colw
        int i4lo = (blockIdx.x * CHUNK) >> 2;
        int i4hi = i4lo + (CHUNK >> 2);
        for (int i = tid; i < NW; i += 256) lh[i] = 0;
        __syncthreads();
        for (int i4 = i4lo + tid; i4 < i4hi; i4 += 256) {
            int4 t = ((const int4*)tgt)[i4];
            atomicAdd(&lh[t.x >> 6], 1);
            atomicAdd(&lh[t.y >> 6], 1);
            atomicAdd(&lh[t.z >> 6], 1);
            atomicAdd(&lh[t.w >> 6], 1);
        }
        __syncthreads();
        for (int i = tid; i < NW; i += 256) {
            int c = lh[i];
            sb[i] = c ? atomicAdd(&wcur[i], c) : 0;
            lh[i] = 0;
        }
        __syncthreads();
        for (int i4 = i4lo + tid; i4 < i4hi; i4 += 256) {
            int4 t = ((const int4*)tgt)[i4];
            int4 s = ((const int4*)src)[i4];
            int w0 = t.x >> 6, r0 = atomicAdd(&lh[w0], 1);
            colw[sb[w0] + r0] = (s.x << 6) | (t.x & 63);
            int w1 = t.y >> 6, r1 = atomicAdd(&lh[w1], 1);
            colw[sb[w1] + r1] = (s.y << 6) | (t.y & 63);
            int w2 = t.z >> 6, r2 = atomicAdd(&lh[w2], 1);
            colw[sb[w2] + r2] = (s.z << 6) | (t.z & 63);
            int w3 = t.w >> 6, r3 = atomicAdd(&lh[w3], 1);
            colw[sb[w3] + r3] = (s.w << 6) | (t.w & 63);
        }
        return;
    }

    // ---- in_proj1: x -> h1 (LDS) -> p1, r1 via MFMA ----
    int node0 = (blockIdx.x - WFB) * 32;
    int lane = tid & 63;
    int wv = tid >> 6;
    int r = lane & 15;
    int q = lane >> 4;

    f16x8 b1[2][3];
#pragma unroll
    for (int nt = 0; nt < 2; nt++) {
        int c = (2 * wv + nt) * 16 + r;
#pragma unroll
        for (int ks = 0; ks < 3; ks++)
            b1[nt][ks] = *(const f16x8*)&WinT[c * 104 + ks * 32 + q * 8];
    }
    // float4-vectorized x staging
    for (int i = tid; i < 672; i += 256) {
        int nd = i / 21, k4 = i - nd * 21;
        int g = node0 + nd;
        float4 v = make_float4(0.f, 0.f, 0.f, 0.f);
        if (g < N) v = ((const float4*)x)[(size_t)g * 21 + k4];
        f16* dst = &xs[nd * 104 + k4 * 4];
        dst[0] = (f16)v.x; dst[1] = (f16)v.y; dst[2] = (f16)v.z; dst[3] = (f16)v.w;
    }
    for (int i = tid; i < 32 * 12; i += 256) {
        int nd = i / 12, k = 84 + (i - nd * 12);
        xs[nd * 104 + k] = (f16)0.f;
    }
    __syncthreads();

    f32x4 acc[2][2] = {};
#pragma unroll
    for (int ks = 0; ks < 3; ks++) {
        int k0 = ks * 32;
        f16x8 a[2];
#pragma unroll
        for (int mt = 0; mt < 2; mt++)
            a[mt] = *(const f16x8*)&xs[(mt * 16 + r) * 104 + k0 + q * 8];
#pragma unroll
        for (int mt = 0; mt < 2; mt++)
#pragma unroll
            for (int nt = 0; nt < 2; nt++)
                acc[mt][nt] = __builtin_amdgcn_mfma_f32_16x16x32_f16(a[mt], b1[nt][ks], acc[mt][nt], 0, 0, 0);
    }

    f16x8 b2[2][4];
#pragma unroll
    for (int nt = 0; nt < 2; nt++) {
        int c = (2 * wv + nt) * 16 + r;
#pragma unroll
        for (int ks = 0; ks < 4; ks++)
            b2[nt][ks] = *(const f16x8*)&W2T[c * 136 + ks * 32 + q * 8];
    }

#pragma unroll
    for (int nt = 0; nt < 2; nt++) {
        int c = (2 * wv + nt) * 16 + r;
        float bb = bin[c];
#pragma unroll
        for (int mt = 0; mt < 2; mt++)
#pragma unroll
            for (int v = 0; v < 4; v++) {
                int row = mt * 16 + q * 4 + v;
                float val = acc[mt][nt][v] + bb;
                hs[row * 136 + c] = (f16)(val > 0.f ? val : 0.f);
            }
    }
    __syncthreads();

    f32x4 acc2[2][2] = {};
#pragma unroll
    for (int ks = 0; ks < 4; ks++) {
        int k0 = ks * 32;
        f16x8 a[2];
#pragma unroll
        for (int mt = 0; mt < 2; mt++)
            a[mt] = *(const f16x8*)&hs[(mt * 16 + r) * 136 + k0 + q * 8];
#pragma unroll
        for (int mt = 0; mt < 2; mt++)
#pragma unroll
            for (int nt = 0; nt < 2; nt++)
                acc2[mt][nt] = __builtin_amdgcn_mfma_f32_16x16x32_f16(a[mt], b2[nt][ks], acc2[mt][nt], 0, 0, 0);
    }

    // epilogue 2: repack into hs (dead after GEMM2), then coalesced f16x8 stores
    __syncthreads();   // all GEMM2 reads of hs complete
#pragma unroll
    for (int nt = 0; nt < 2; nt++) {
        int c = (2 * wv + nt) * 16 + r;
        float bb = (c >= 64) ? bl[c - 64] : 0.f;
#pragma unroll
        for (int mt = 0; mt < 2; mt++)
#pragma unroll
            for (int v = 0; v < 4; v++) {
                int row = mt * 16 + q * 4 + v;
                hs[row * 136 + c] = (f16)(acc2[mt][nt][v] + bb);
            }
    }
    __syncthreads();
    {
        int row = tid >> 3, c8 = tid & 7;   // 32 rows x 8 chunks
        int n = node0 + row;
        if (n < N) {
            f16x8 vp = *(const f16x8*)&hs[row * 136 + c8 * 8];
            *(f16x8*)&p1h[(size_t)n * 64 + c8 * 8] = vp;
            f16x8 vr = *(const f16x8*)&hs[row * 136 + 64 + c8 * 8];
            *(f16x8*)&r1h[(size_t)n * 64 + c8 * 8] = vr;
        }
    }
}

#define F2ADD(a, b) { (a).x += (b).x; (a).y += (b).y; }

// ---------------- agg1 (per-window): L2-warm + LDS sort -> gather+LN -> MFMA proj2 ----------------
__global__ __launch_bounds__(512) void k_agg1_proj2(const __half2* __restrict__ p1v,
                                                    const __half2* __restrict__ r1v,
                                                    const int* __restrict__ wcur,
                                                    const int* __restrict__ colw,
                                                    const float* __restrict__ g1,
                                                    const float* __restrict__ be1,
                                                    const f16* __restrict__ W3T,
                                                    const float* __restrict__ bl2,
                                                    f16* __restrict__ p2h,
                                                    f16* __restrict__ r2h, int N) {
    __shared__ int cnt[64], start[64], cur[64];
    __shared__ int sorted[CAP];
    __shared__ __align__(16) f16 ys[64][72];
    int tid = threadIdx.x;
    int wb = blockIdx.x;
    int base = wb * CAP;
    int nb = wb << 6;
    int len = wcur[wb] - base;
    if (len > CAP) len = CAP;

    // stream first 3.5 MB of p1 into this XCD's L2 (cache-sized prefix)
    l2_warm((const uint4*)p1v, 229376, wb, tid, 512);

    unsigned cc = tid & 31;
    int grp = tid >> 5;       // 16 groups of 32 lanes
    int lane = tid & 63;
    int wv = tid >> 6;        // 8 waves
    int r = lane & 15;
    int q = lane >> 4;

    int mt = wv & 3;
    int ntbase = (wv >> 2) * 2;
    f16x8 b3[2][2];
#pragma unroll
    for (int j = 0; j < 2; j++)
#pragma unroll
        for (int ks = 0; ks < 2; ks++)
            b3[j][ks] = *(const f16x8*)&W3T[((ntbase + j) * 16 + r) * 72 + ks * 32 + q * 8];

    // ---- per-window counting sort in LDS ----
    if (tid < 64) cnt[tid] = 0;
    __syncthreads();
    for (int i = tid; i < len; i += 512) atomicAdd(&cnt[colw[base + i] & 63], 1);
    __syncthreads();
    if (tid < 64) {
        int v = cnt[tid];
        int incl = waveInclScan(v, tid);
        start[tid] = incl - v;
        cur[tid] = incl - v;
    }
    __syncthreads();
    for (int i = tid; i < len; i += 512) {
        int pk = colw[base + i];
        int pos = atomicAdd(&cur[pk & 63], 1);
        sorted[pos] = pk >> 6;
    }
    __syncthreads();

    // ---- gather + LN + relu: 4 nodes per 32-lane group ----
#pragma unroll
    for (int t = 0; t < 4; t++) {
        int tl = grp + 16 * t;
        int n = nb + tl;
        if (n < N) {
            int s0 = start[tl], s1 = start[tl] + cnt[tl];
            float2 a0 = make_float2(0.f, 0.f), a1 = a0, a2 = a0, a3 = a0;
            float2 a4 = a0, a5 = a0, a6 = a0, a7 = a0;
            int i = s0;
            for (; i + 7 < s1; i += 8) {
                unsigned c0 = sorted[i],     c1 = sorted[i + 1], c2 = sorted[i + 2], c3 = sorted[i + 3];
                unsigned c4 = sorted[i + 4], c5 = sorted[i + 5], c6 = sorted[i + 6], c7 = sorted[i + 7];
                float2 v0 = __half22float2(p1v[c0 * 32u + cc]);
                float2 v1 = __half22float2(p1v[c1 * 32u + cc]);
                float2 v2 = __half22float2(p1v[c2 * 32u + cc]);
                float2 v3 = __half22float2(p1v[c3 * 32u + cc]);
                float2 v4 = __half22float2(p1v[c4 * 32u + cc]);
                float2 v5 = __half22float2(p1v[c5 * 32u + cc]);
                float2 v6 = __half22float2(p1v[c6 * 32u + cc]);
                float2 v7 = __half22float2(p1v[c7 * 32u + cc]);
                F2ADD(a0, v0) F2ADD(a1, v1) F2ADD(a2, v2) F2ADD(a3, v3)
                F2ADD(a4, v4) F2ADD(a5, v5) F2ADD(a6, v6) F2ADD(a7, v7)
            }
            for (; i < s1; i++) {
                float2 v0 = __half22float2(p1v[(unsigned)sorted[i] * 32u + cc]);
                F2ADD(a0, v0)
            }
            F2ADD(a0, a4) F2ADD(a1, a5) F2ADD(a2, a6) F2ADD(a3, a7)
            F2ADD(a0, a2) F2ADD(a1, a3) F2ADD(a0, a1)
            int cntv = s1 - s0;
            float inv = 1.f / (float)(cntv > 1 ? cntv : 1);
            float2 rr = __half22float2(r1v[(unsigned)n * 32u + cc]);
            float vx = a0.x * inv + rr.x;
            float vy = a0.y * inv + rr.y;
            float s = vx + vy;
#pragma unroll
            for (int o = 1; o < 32; o <<= 1) s += __shfl_xor(s, o, 32);
            float m = s * (1.f / 64.f);
            float dx = vx - m, dy = vy - m;
            float qv = dx * dx + dy * dy;
#pragma unroll
            for (int o = 1; o < 32; o <<= 1) qv += __shfl_xor(qv, o, 32);
            float rs = rsqrtf(qv * (1.f / 64.f) + EPS);
            float y0 = dx * rs * g1[2 * cc] + be1[2 * cc];
            float y1 = dy * rs * g1[2 * cc + 1] + be1[2 * cc + 1];
            ys[tl][2 * cc]     = (f16)(y0 > 0.f ? y0 : 0.f);
            ys[tl][2 * cc + 1] = (f16)(y1 > 0.f ? y1 : 0.f);
        } else {
            ys[tl][2 * cc] = (f16)0.f;
            ys[tl][2 * cc + 1] = (f16)0.f;
        }
    }
    __syncthreads();

    // ---- proj2 via MFMA: [64 x 64] @ [64 x 64], 16 tile-jobs, 2 per wave ----
#pragma unroll
    for (int j = 0; j < 2; j++) {
        int nt = ntbase + j;
        f32x4 acc = {};
#pragma unroll
        for (int ks = 0; ks < 2; ks++) {
            f16x8 a = *(const f16x8*)&ys[mt * 16 + r][ks * 32 + q * 8];
            acc = __builtin_amdgcn_mfma_f32_16x16x32_f16(a, b3[j][ks], acc, 0, 0, 0);
        }
        int c2 = nt * 16 + r;
        float bb = (c2 >= 32) ? bl2[c2 - 32] : 0.f;
#pragma unroll
        for (int v = 0; v < 4; v++) {
            int n = nb + mt * 16 + q * 4 + v;
            if (n < N) {
                float val = acc[v];
                if (c2 < 32) p2h[(size_t)n * 32 + c2] = (f16)val;
                else         r2h[(size_t)n * 32 + (c2 - 32)] = (f16)(val + bb);
            }
        }
    }
}

// ---------------- agg2 (per-window): L2-warm + LDS sort -> gather+LN -> MFMA MLP ----------------
__global__ __launch_bounds__(512) void k_agg2_out(const __half2* __restrict__ p2v,
                                                  const __half2* __restrict__ r2v,
                                                  const int* __restrict__ wcur,
                                                  const int* __restrict__ colw,
                                                  const float* __restrict__ g2,
                                                  const float* __restrict__ be2,
                                                  const f16* __restrict__ Wo1T,
                                                  const float* __restrict__ bo1,
                                                  const float* __restrict__ Wo2,
                                                  const float* __restrict__ bo2,
                                                  float* __restrict__ out, int N) {
    __shared__ int cnt[64], start[64], cur[64];
    __shared__ int sorted[CAP];
    __shared__ __align__(16) f16 ys[64][40];
    int tid = threadIdx.x;
    int wb = blockIdx.x;
    int base = wb * CAP;
    int nb = wb << 6;
    int len = wcur[wb] - base;
    if (len > CAP) len = CAP;

    // stream all of p2 (3.2 MB, L2-fits) into this XCD's L2
    l2_warm((const uint4*)p2v, 200000, wb, tid, 512);

    unsigned l = tid & 15;
    int grp = tid >> 4;       // 32 groups of 16 lanes
    int lane = tid & 63;
    int wv = tid >> 6;        // 8 waves; waves 0..3 do the MFMA
    int r = lane & 15;
    int q = lane >> 4;

    f16x8 bo = *(const f16x8*)&Wo1T[r * 40 + q * 8];
    float b1v = bo1[r];
    float w2v = Wo2[r];

    if (tid < 64) cnt[tid] = 0;
    __syncthreads();
    for (int i = tid; i < len; i += 512) atomicAdd(&cnt[colw[base + i] & 63], 1);
    __syncthreads();
    if (tid < 64) {
        int v = cnt[tid];
        int incl = waveInclScan(v, tid);
        start[tid] = incl - v;
        cur[tid] = incl - v;
    }
    __syncthreads();
    for (int i = tid; i < len; i += 512) {
        int pk = colw[base + i];
        int pos = atomicAdd(&cur[pk & 63], 1);
        sorted[pos] = pk >> 6;
    }
    __syncthreads();

    // gather + LN + relu: 2 nodes per 16-lane group
#pragma unroll
    for (int t = 0; t < 2; t++) {
        int tl = grp + 32 * t;
        int n = nb + tl;
        if (n < N) {
            int s0 = start[tl], s1 = start[tl] + cnt[tl];
            float2 a0 = make_float2(0.f, 0.f), a1 = a0, a2 = a0, a3 = a0;
            float2 a4 = a0, a5 = a0, a6 = a0, a7 = a0;
            int i = s0;
            for (; i + 7 < s1; i += 8) {
                unsigned c0 = sorted[i],     c1 = sorted[i + 1], c2 = sorted[i + 2], c3 = sorted[i + 3];
                unsigned c4 = sorted[i + 4], c5 = sorted[i + 5], c6 = sorted[i + 6], c7 = sorted[i + 7];
                float2 v0 = __half22float2(p2v[c0 * 16u + l]);
                float2 v1 = __half22float2(p2v[c1 * 16u + l]);
                float2 v2 = __half22float2(p2v[c2 * 16u + l]);
                float2 v3 = __half22float2(p2v[c3 * 16u + l]);
                float2 v4 = __half22float2(p2v[c4 * 16u + l]);
                float2 v5 = __half22float2(p2v[c5 * 16u + l]);
                float2 v6 = __half22float2(p2v[c6 * 16u + l]);
                float2 v7 = __half22float2(p2v[c7 * 16u + l]);
                F2ADD(a0, v0) F2ADD(a1, v1) F2ADD(a2, v2) F2ADD(a3, v3)
                F2ADD(a4, v4) F2ADD(a5, v5) F2ADD(a6, v6) F2ADD(a7, v7)
            }
            for (; i < s1; i++) {
                float2 v0 = __half22float2(p2v[(unsigned)sorted[i] * 16u + l]);
                F2ADD(a0, v0)
            }
            F2ADD(a0, a4) F2ADD(a1, a5) F2ADD(a2, a6) F2ADD(a3, a7)
            F2ADD(a0, a2) F2ADD(a1, a3) F2ADD(a0, a1)
            int cntv = s1 - s0;
            float inv = 1.f / (float)(cntv > 1 ? cntv : 1);
            float2 rr = __half22float2(r2v[(unsigned)n * 16u + l]);
            float vx = a0.x * inv + rr.x;
            float vy = a0.y * inv + rr.y;
            float s = vx + vy;
#pragma unroll
            for (int o = 1; o < 16; o <<= 1) s += __shfl_xor(s, o, 16);
            float m = s * (1.f / 32.f);
            float dx = vx - m, dy = vy - m;
            float qv = dx * dx + dy * dy;
#pragma unroll
            for (int o = 1; o < 16; o <<= 1) qv += __shfl_xor(qv, o, 16);
            float rs = rsqrtf(qv * (1.f / 32.f) + EPS);
            float y0 = dx * rs * g2[2 * l] + be2[2 * l];
            float y1 = dy * rs * g2[2 * l + 1] + be2[2 * l + 1];
            ys[tl][2 * l]     = (f16)(y0 > 0.f ? y0 : 0.f);
            ys[tl][2 * l + 1] = (f16)(y1 > 0.f ? y1 : 0.f);
        } else {
            ys[tl][2 * l] = (f16)0.f;
            ys[tl][2 * l + 1] = (f16)0.f;
        }
    }
    __syncthreads();

    // MLP: hidden = relu(y@Wo1+bo1) via MFMA, out = hidden@Wo2 + bo2 via reduce
    if (wv < 4) {
        f16x8 a = *(const f16x8*)&ys[wv * 16 + r][q * 8];
        f32x4 acc = {};
        acc = __builtin_amdgcn_mfma_f32_16x16x32_f16(a, bo, acc, 0, 0, 0);
#pragma unroll
        for (int v = 0; v < 4; v++) {
            float h = acc[v] + b1v;
            h = h > 0.f ? h : 0.f;
            float contrib = h * w2v;
#pragma unroll
            for (int o = 1; o < 16; o <<= 1) contrib += __shfl_xor(contrib, o, 16);
            int n = nb + wv * 16 + q * 4 + v;
            if (r == 0 && n < N) out[n] = contrib + bo2[0];
        }
    }
}

extern "C" void kernel_launch(void* const* d_in, const int* in_sizes, int n_in,
                              void* d_out, int out_size, void* d_ws, size_t ws_size,
                              hipStream_t stream) {
    const float* x    = (const float*)d_in[0];
    const int*   ei   = (const int*)d_in[1];
    const float* W_in = (const float*)d_in[2];
    const float* b_in = (const float*)d_in[3];
    const float* Wl1  = (const float*)d_in[4];
    const float* bl1  = (const float*)d_in[5];
    const float* Wr1  = (const float*)d_in[6];
    const float* g1   = (const float*)d_in[7];
    const float* be1  = (const float*)d_in[8];
    const float* Wl2  = (const float*)d_in[9];
    const float* bl2  = (const float*)d_in[10];
    const float* Wr2  = (const float*)d_in[11];
    const float* g2   = (const float*)d_in[12];
    const float* be2  = (const float*)d_in[13];
    const float* Wo1  = (const float*)d_in[14];
    const float* bo1  = (const float*)d_in[15];
    const float* Wo2  = (const float*)d_in[16];
    const float* bo2  = (const float*)d_in[17];
    float* out = (float*)d_out;

    const int N = NN, E = NE;
    const int* src = ei;
    const int* tgt = ei + E;

    // workspace layout
    char* w = (char*)d_ws;
    int* wcur = (int*)w;  w += (size_t)NW * 4;
    w = (char*)(((uintptr_t)w + 15) & ~(uintptr_t)15);
    int* colw = (int*)w;  w += (size_t)NW * CAP * 4;     // 8.0 MB, CAP-strided
    f16* p1h  = (f16*)w;  w += (size_t)N * 64 * 2;
    f16* r1h  = (f16*)w;  w += (size_t)N * 64 * 2;
    f16* p2h  = (f16*)w;  w += (size_t)N * 32 * 2;
    f16* r2h  = (f16*)w;  w += (size_t)N * 32 * 2;
    f16* WinT = (f16*)w;  w += (size_t)128 * 104 * 2;
    f16* W2T  = (f16*)w;  w += (size_t)128 * 136 * 2;
    f16* W3T  = (f16*)w;  w += (size_t)64 * 72 * 2;
    f16* Wo1T = (f16*)w;  w += (size_t)16 * 40 * 2;

    // ---- 4-dispatch pipeline ----
    k_prep_init<<<PREPB, 256, 0, stream>>>(W_in, Wl1, Wr1, Wl2, Wr2, Wo1,
                                           WinT, W2T, W3T, Wo1T, wcur);
    k_wfill_inproj<<<WFB + INPB, 256, 0, stream>>>(src, tgt, wcur, colw,
                                                   x, WinT, b_in, W2T, bl1, p1h, r1h, N);
    k_agg1_proj2<<<NW, 512, 0, stream>>>((const __half2*)p1h, (const __half2*)r1h,
                                         wcur, colw, g1, be1, W3T, bl2, p2h, r2h, N);
    k_agg2_out<<<NW, 512, 0, stream>>>((const __half2*)p2h, (const __half2*)r2h,
                                       wcur, colw, g2, be2, Wo1T, bo1, Wo2, bo2, out, N);
}

// Round 14
// 82.634 us; speedup vs baseline: 1.0697x; 1.0697x over previous
//
#include <hip/hip_runtime.h>
#include <hip/hip_bf16.h>
#include <hip/hip_fp16.h>

#define NN 50000
#define NE 800000
#define EPS 1e-5f
#define NW 782            // ceil(NN/64) windows of 64 nodes
#define CAP 2560          // fixed per-window colw slots (max window load ~1150)
#define WFB 200           // wfill blocks
#define CHUNK (NE / WFB)  // 4000 edges per wfill block
#define PREPB 64          // prep blocks
#define INPB ((NN + 31) / 32)

typedef _Float16 f16;
typedef _Float16 f16x8 __attribute__((ext_vector_type(8)));
typedef float f32x4 __attribute__((ext_vector_type(4)));

__device__ __forceinline__ int waveInclScan(int v, int lane) {
#pragma unroll
    for (int o = 1; o < 64; o <<= 1) {
        int t = __shfl_up(v, o, 64);
        if (lane >= o) v += t;
    }
    return v;
}

// ---------------- prep: weight transposes + wcur init ----------------
__global__ __launch_bounds__(256) void k_prep_init(const float* __restrict__ Win,
                                                   const float* __restrict__ Wl,
                                                   const float* __restrict__ Wr,
                                                   const float* __restrict__ Wl2,
                                                   const float* __restrict__ Wr2,
                                                   const float* __restrict__ Wo1,
                                                   f16* __restrict__ WinT,
                                                   f16* __restrict__ W2T,
                                                   f16* __restrict__ W3T,
                                                   f16* __restrict__ Wo1T,
                                                   int* __restrict__ wcur) {
    int i0 = blockIdx.x * 256 + threadIdx.x;
    for (int i = i0; i < 128 * 104; i += PREPB * 256) {
        int c = i / 104, k = i - c * 104;
        float v = (k < 84) ? Win[k * 128 + c] : 0.f;
        WinT[c * 104 + k] = (f16)v;
    }
    for (int i = i0; i < 128 * 136; i += PREPB * 256) {
        int c = i / 136, k = i - c * 136;
        float v = 0.f;
        if (k < 128) v = (c < 64) ? Wl[k * 64 + c] : Wr[k * 64 + (c - 64)];
        W2T[c * 136 + k] = (f16)v;
    }
    for (int i = i0; i < 64 * 72; i += PREPB * 256) {
        int c = i / 72, k = i - c * 72;
        float v = 0.f;
        if (k < 64) v = (c < 32) ? Wl2[k * 32 + c] : Wr2[k * 32 + (c - 32)];
        W3T[c * 72 + k] = (f16)v;
    }
    for (int i = i0; i < 16 * 40; i += PREPB * 256) {
        int c = i / 40, k = i - c * 40;
        float v = (k < 32) ? Wo1[k * 16 + c] : 0.f;
        Wo1T[c * 40 + k] = (f16)v;
    }
    for (int i = i0; i < NW; i += PREPB * 256) wcur[i] = i * CAP;
}

// ---------------- fused: wfill (blocks <WFB) | MFMA in_proj1 (rest) ----------------
__global__ __launch_bounds__(256) void k_wfill_inproj(const int* __restrict__ src,
                                                      const int* __restrict__ tgt,
                                                      int* __restrict__ wcur,
                                                      int* __restrict__ colw,
                                                      const float* __restrict__ x,
                                                      const f16* __restrict__ WinT,
                                                      const float* __restrict__ bin,
                                                      const f16* __restrict__ W2T,
                                                      const float* __restrict__ bl,
                                                      f16* __restrict__ p1h,
                                                      f16* __restrict__ r1h, int N) {
    __shared__ int lh[NW];
    __shared__ int sb[NW];
    __shared__ __align__(16) f16 xs[32 * 104];
    __shared__ __align__(16) f16 hs[32 * 136];
    int tid = threadIdx.x;

    if (blockIdx.x < WFB) {
        // span-reserved window partition into CAP-strided colw
        int i4lo = (blockIdx.x * CHUNK) >> 2;
        int i4hi = i4lo + (CHUNK >> 2);
        for (int i = tid; i < NW; i += 256) lh[i] = 0;
        __syncthreads();
        for (int i4 = i4lo + tid; i4 < i4hi; i4 += 256) {
            int4 t = ((const int4*)tgt)[i4];
            atomicAdd(&lh[t.x >> 6], 1);
            atomicAdd(&lh[t.y >> 6], 1);
            atomicAdd(&lh[t.z >> 6], 1);
            atomicAdd(&lh[t.w >> 6], 1);
        }
        __syncthreads();
        for (int i = tid; i < NW; i += 256) {
            int c = lh[i];
            sb[i] = c ? atomicAdd(&wcur[i], c) : 0;
            lh[i] = 0;
        }
        __syncthreads();
        for (int i4 = i4lo + tid; i4 < i4hi; i4 += 256) {
            int4 t = ((const int4*)tgt)[i4];
            int4 s = ((const int4*)src)[i4];
            int w0 = t.x >> 6, r0 = atomicAdd(&lh[w0], 1);
            colw[sb[w0] + r0] = (s.x << 6) | (t.x & 63);
            int w1 = t.y >> 6, r1 = atomicAdd(&lh[w1], 1);
            colw[sb[w1] + r1] = (s.y << 6) | (t.y & 63);
            int w2 = t.z >> 6, r2 = atomicAdd(&lh[w2], 1);
            colw[sb[w2] + r2] = (s.z << 6) | (t.z & 63);
            int w3 = t.w >> 6, r3 = atomicAdd(&lh[w3], 1);
            colw[sb[w3] + r3] = (s.w << 6) | (t.w & 63);
        }
        return;
    }

    // ---- in_proj1: x -> h1 (LDS) -> p1, r1 via MFMA ----
    int node0 = (blockIdx.x - WFB) * 32;
    int lane = tid & 63;
    int wv = tid >> 6;
    int r = lane & 15;
    int q = lane >> 4;

    f16x8 b1[2][3];
#pragma unroll
    for (int nt = 0; nt < 2; nt++) {
        int c = (2 * wv + nt) * 16 + r;
#pragma unroll
        for (int ks = 0; ks < 3; ks++)
            b1[nt][ks] = *(const f16x8*)&WinT[c * 104 + ks * 32 + q * 8];
    }
    // float4-vectorized x staging
    for (int i = tid; i < 672; i += 256) {
        int nd = i / 21, k4 = i - nd * 21;
        int g = node0 + nd;
        float4 v = make_float4(0.f, 0.f, 0.f, 0.f);
        if (g < N) v = ((const float4*)x)[(size_t)g * 21 + k4];
        f16* dst = &xs[nd * 104 + k4 * 4];
        dst[0] = (f16)v.x; dst[1] = (f16)v.y; dst[2] = (f16)v.z; dst[3] = (f16)v.w;
    }
    for (int i = tid; i < 32 * 12; i += 256) {
        int nd = i / 12, k = 84 + (i - nd * 12);
        xs[nd * 104 + k] = (f16)0.f;
    }
    __syncthreads();

    f32x4 acc[2][2] = {};
#pragma unroll
    for (int ks = 0; ks < 3; ks++) {
        int k0 = ks * 32;
        f16x8 a[2];
#pragma unroll
        for (int mt = 0; mt < 2; mt++)
            a[mt] = *(const f16x8*)&xs[(mt * 16 + r) * 104 + k0 + q * 8];
#pragma unroll
        for (int mt = 0; mt < 2; mt++)
#pragma unroll
            for (int nt = 0; nt < 2; nt++)
                acc[mt][nt] = __builtin_amdgcn_mfma_f32_16x16x32_f16(a[mt], b1[nt][ks], acc[mt][nt], 0, 0, 0);
    }

    f16x8 b2[2][4];
#pragma unroll
    for (int nt = 0; nt < 2; nt++) {
        int c = (2 * wv + nt) * 16 + r;
#pragma unroll
        for (int ks = 0; ks < 4; ks++)
            b2[nt][ks] = *(const f16x8*)&W2T[c * 136 + ks * 32 + q * 8];
    }

#pragma unroll
    for (int nt = 0; nt < 2; nt++) {
        int c = (2 * wv + nt) * 16 + r;
        float bb = bin[c];
#pragma unroll
        for (int mt = 0; mt < 2; mt++)
#pragma unroll
            for (int v = 0; v < 4; v++) {
                int row = mt * 16 + q * 4 + v;
                float val = acc[mt][nt][v] + bb;
                hs[row * 136 + c] = (f16)(val > 0.f ? val : 0.f);
            }
    }
    __syncthreads();

    f32x4 acc2[2][2] = {};
#pragma unroll
    for (int ks = 0; ks < 4; ks++) {
        int k0 = ks * 32;
        f16x8 a[2];
#pragma unroll
        for (int mt = 0; mt < 2; mt++)
            a[mt] = *(const f16x8*)&hs[(mt * 16 + r) * 136 + k0 + q * 8];
#pragma unroll
        for (int mt = 0; mt < 2; mt++)
#pragma unroll
            for (int nt = 0; nt < 2; nt++)
                acc2[mt][nt] = __builtin_amdgcn_mfma_f32_16x16x32_f16(a[mt], b2[nt][ks], acc2[mt][nt], 0, 0, 0);
    }

    // epilogue 2: repack into hs (dead after GEMM2), then coalesced f16x8 stores
    __syncthreads();
#pragma unroll
    for (int nt = 0; nt < 2; nt++) {
        int c = (2 * wv + nt) * 16 + r;
        float bb = (c >= 64) ? bl[c - 64] : 0.f;
#pragma unroll
        for (int mt = 0; mt < 2; mt++)
#pragma unroll
            for (int v = 0; v < 4; v++) {
                int row = mt * 16 + q * 4 + v;
                hs[row * 136 + c] = (f16)(acc2[mt][nt][v] + bb);
            }
    }
    __syncthreads();
    {
        int row = tid >> 3, c8 = tid & 7;   // 32 rows x 8 chunks
        int n = node0 + row;
        if (n < N) {
            f16x8 vp = *(const f16x8*)&hs[row * 136 + c8 * 8];
            *(f16x8*)&p1h[(size_t)n * 64 + c8 * 8] = vp;
            f16x8 vr = *(const f16x8*)&hs[row * 136 + 64 + c8 * 8];
            *(f16x8*)&r1h[(size_t)n * 64 + c8 * 8] = vr;
        }
    }
}

#define F2ADD(a, b) { (a).x += (b).x; (a).y += (b).y; }

// ---------------- agg1 (per-window, one block): LDS sort -> gather+LN -> MFMA proj2 ----------------
__global__ __launch_bounds__(512) void k_agg1_proj2(const __half2* __restrict__ p1v,
                                                    const __half2* __restrict__ r1v,
                                                    const int* __restrict__ wcur,
                                                    const int* __restrict__ colw,
                                                    const float* __restrict__ g1,
                                                    const float* __restrict__ be1,
                                                    const f16* __restrict__ W3T,
                                                    const float* __restrict__ bl2,
                                                    f16* __restrict__ p2h,
                                                    f16* __restrict__ r2h, int N) {
    __shared__ int cnt[64], start[64], cur[64];
    __shared__ int sorted[CAP];
    __shared__ __align__(16) f16 ys[64][72];
    int tid = threadIdx.x;
    int wb = blockIdx.x;
    int base = wb * CAP;
    int nb = wb << 6;
    int len = wcur[wb] - base;
    if (len > CAP) len = CAP;

    unsigned cc = tid & 31;
    int grp = tid >> 5;       // 16 groups of 32 lanes
    int lane = tid & 63;
    int wv = tid >> 6;        // 8 waves
    int r = lane & 15;
    int q = lane >> 4;

    // proj2 B-fragments hoisted (overlaps with sort/gather latency)
    int mt = wv & 3;
    int ntbase = (wv >> 2) * 2;
    f16x8 b3[2][2];
#pragma unroll
    for (int j = 0; j < 2; j++)
#pragma unroll
        for (int ks = 0; ks < 2; ks++)
            b3[j][ks] = *(const f16x8*)&W3T[((ntbase + j) * 16 + r) * 72 + ks * 32 + q * 8];

    // ---- per-window counting sort in LDS ----
    if (tid < 64) cnt[tid] = 0;
    __syncthreads();
    for (int i = tid; i < len; i += 512) atomicAdd(&cnt[colw[base + i] & 63], 1);
    __syncthreads();
    if (tid < 64) {
        int v = cnt[tid];
        int incl = waveInclScan(v, tid);
        start[tid] = incl - v;
        cur[tid] = incl - v;
    }
    __syncthreads();
    for (int i = tid; i < len; i += 512) {
        int pk = colw[base + i];
        int pos = atomicAdd(&cur[pk & 63], 1);
        sorted[pos] = pk >> 6;
    }
    __syncthreads();

    // ---- gather + LN + relu: 4 nodes per 32-lane group ----
#pragma unroll
    for (int t = 0; t < 4; t++) {
        int tl = grp + 16 * t;
        int n = nb + tl;
        if (n < N) {
            int s0 = start[tl], s1 = start[tl] + cnt[tl];
            float2 a0 = make_float2(0.f, 0.f), a1 = a0, a2 = a0, a3 = a0;
            float2 a4 = a0, a5 = a0, a6 = a0, a7 = a0;
            int i = s0;
            for (; i + 7 < s1; i += 8) {
                unsigned c0 = sorted[i],     c1 = sorted[i + 1], c2 = sorted[i + 2], c3 = sorted[i + 3];
                unsigned c4 = sorted[i + 4], c5 = sorted[i + 5], c6 = sorted[i + 6], c7 = sorted[i + 7];
                float2 v0 = __half22float2(p1v[c0 * 32u + cc]);
                float2 v1 = __half22float2(p1v[c1 * 32u + cc]);
                float2 v2 = __half22float2(p1v[c2 * 32u + cc]);
                float2 v3 = __half22float2(p1v[c3 * 32u + cc]);
                float2 v4 = __half22float2(p1v[c4 * 32u + cc]);
                float2 v5 = __half22float2(p1v[c5 * 32u + cc]);
                float2 v6 = __half22float2(p1v[c6 * 32u + cc]);
                float2 v7 = __half22float2(p1v[c7 * 32u + cc]);
                F2ADD(a0, v0) F2ADD(a1, v1) F2ADD(a2, v2) F2ADD(a3, v3)
                F2ADD(a4, v4) F2ADD(a5, v5) F2ADD(a6, v6) F2ADD(a7, v7)
            }
            for (; i < s1; i++) {
                float2 v0 = __half22float2(p1v[(unsigned)sorted[i] * 32u + cc]);
                F2ADD(a0, v0)
            }
            F2ADD(a0, a4) F2ADD(a1, a5) F2ADD(a2, a6) F2ADD(a3, a7)
            F2ADD(a0, a2) F2ADD(a1, a3) F2ADD(a0, a1)
            int cntv = s1 - s0;
            float inv = 1.f / (float)(cntv > 1 ? cntv : 1);
            float2 rr = __half22float2(r1v[(unsigned)n * 32u + cc]);
            float vx = a0.x * inv + rr.x;
            float vy = a0.y * inv + rr.y;
            float s = vx + vy;
#pragma unroll
            for (int o = 1; o < 32; o <<= 1) s += __shfl_xor(s, o, 32);
            float m = s * (1.f / 64.f);
            float dx = vx - m, dy = vy - m;
            float qv = dx * dx + dy * dy;
#pragma unroll
            for (int o = 1; o < 32; o <<= 1) qv += __shfl_xor(qv, o, 32);
            float rs = rsqrtf(qv * (1.f / 64.f) + EPS);
            float y0 = dx * rs * g1[2 * cc] + be1[2 * cc];
            float y1 = dy * rs * g1[2 * cc + 1] + be1[2 * cc + 1];
            ys[tl][2 * cc]     = (f16)(y0 > 0.f ? y0 : 0.f);
            ys[tl][2 * cc + 1] = (f16)(y1 > 0.f ? y1 : 0.f);
        } else {
            ys[tl][2 * cc] = (f16)0.f;
            ys[tl][2 * cc + 1] = (f16)0.f;
        }
    }
    __syncthreads();

    // ---- proj2 via MFMA: [64 x 64] @ [64 x 64], 16 tile-jobs, 2 per wave ----
#pragma unroll
    for (int j = 0; j < 2; j++) {
        int nt = ntbase + j;
        f32x4 acc = {};
#pragma unroll
        for (int ks = 0; ks < 2; ks++) {
            f16x8 a = *(const f16x8*)&ys[mt * 16 + r][ks * 32 + q * 8];
            acc = __builtin_amdgcn_mfma_f32_16x16x32_f16(a, b3[j][ks], acc, 0, 0, 0);
        }
        int c2 = nt * 16 + r;
        float bb = (c2 >= 32) ? bl2[c2 - 32] : 0.f;
#pragma unroll
        for (int v = 0; v < 4; v++) {
            int n = nb + mt * 16 + q * 4 + v;
            if (n < N) {
                float val = acc[v];
                if (c2 < 32) p2h[(size_t)n * 32 + c2] = (f16)val;
                else         r2h[(size_t)n * 32 + (c2 - 32)] = (f16)(val + bb);
            }
        }
    }
}

// ---------------- agg2 (per-window, one block): LDS sort -> gather+LN -> MFMA MLP ----------------
__global__ __launch_bounds__(512) void k_agg2_out(const __half2* __restrict__ p2v,
                                                  const __half2* __restrict__ r2v,
                                                  const int* __restrict__ wcur,
                                                  const int* __restrict__ colw,
                                                  const float* __restrict__ g2,
                                                  const float* __restrict__ be2,
                                                  const f16* __restrict__ Wo1T,
                                                  const float* __restrict__ bo1,
                                                  const float* __restrict__ Wo2,
                                                  const float* __restrict__ bo2,
                                                  float* __restrict__ out, int N) {
    __shared__ int cnt[64], start[64], cur[64];
    __shared__ int sorted[CAP];
    __shared__ __align__(16) f16 ys[64][40];
    int tid = threadIdx.x;
    int wb = blockIdx.x;
    int base = wb * CAP;
    int nb = wb << 6;
    int len = wcur[wb] - base;
    if (len > CAP) len = CAP;

    unsigned l = tid & 15;
    int grp = tid >> 4;       // 32 groups of 16 lanes
    int lane = tid & 63;
    int wv = tid >> 6;        // 8 waves; waves 0..3 do the MFMA
    int r = lane & 15;
    int q = lane >> 4;

    f16x8 bo = *(const f16x8*)&Wo1T[r * 40 + q * 8];
    float b1v = bo1[r];
    float w2v = Wo2[r];

    if (tid < 64) cnt[tid] = 0;
    __syncthreads();
    for (int i = tid; i < len; i += 512) atomicAdd(&cnt[colw[base + i] & 63], 1);
    __syncthreads();
    if (tid < 64) {
        int v = cnt[tid];
        int incl = waveInclScan(v, tid);
        start[tid] = incl - v;
        cur[tid] = incl - v;
    }
    __syncthreads();
    for (int i = tid; i < len; i += 512) {
        int pk = colw[base + i];
        int pos = atomicAdd(&cur[pk & 63], 1);
        sorted[pos] = pk >> 6;
    }
    __syncthreads();

    // gather + LN + relu: 2 nodes per 16-lane group
#pragma unroll
    for (int t = 0; t < 2; t++) {
        int tl = grp + 32 * t;
        int n = nb + tl;
        if (n < N) {
            int s0 = start[tl], s1 = start[tl] + cnt[tl];
            float2 a0 = make_float2(0.f, 0.f), a1 = a0, a2 = a0, a3 = a0;
            float2 a4 = a0, a5 = a0, a6 = a0, a7 = a0;
            int i = s0;
            for (; i + 7 < s1; i += 8) {
                unsigned c0 = sorted[i],     c1 = sorted[i + 1], c2 = sorted[i + 2], c3 = sorted[i + 3];
                unsigned c4 = sorted[i + 4], c5 = sorted[i + 5], c6 = sorted[i + 6], c7 = sorted[i + 7];
                float2 v0 = __half22float2(p2v[c0 * 16u + l]);
                float2 v1 = __half22float2(p2v[c1 * 16u + l]);
                float2 v2 = __half22float2(p2v[c2 * 16u + l]);
                float2 v3 = __half22float2(p2v[c3 * 16u + l]);
                float2 v4 = __half22float2(p2v[c4 * 16u + l]);
                float2 v5 = __half22float2(p2v[c5 * 16u + l]);
                float2 v6 = __half22float2(p2v[c6 * 16u + l]);
                float2 v7 = __half22float2(p2v[c7 * 16u + l]);
                F2ADD(a0, v0) F2ADD(a1, v1) F2ADD(a2, v2) F2ADD(a3, v3)
                F2ADD(a4, v4) F2ADD(a5, v5) F2ADD(a6, v6) F2ADD(a7, v7)
            }
            for (; i < s1; i++) {
                float2 v0 = __half22float2(p2v[(unsigned)sorted[i] * 16u + l]);
                F2ADD(a0, v0)
            }
            F2ADD(a0, a4) F2ADD(a1, a5) F2ADD(a2, a6) F2ADD(a3, a7)
            F2ADD(a0, a2) F2ADD(a1, a3) F2ADD(a0, a1)
            int cntv = s1 - s0;
            float inv = 1.f / (float)(cntv > 1 ? cntv : 1);
            float2 rr = __half22float2(r2v[(unsigned)n * 16u + l]);
            float vx = a0.x * inv + rr.x;
            float vy = a0.y * inv + rr.y;
            float s = vx + vy;
#pragma unroll
            for (int o = 1; o < 16; o <<= 1) s += __shfl_xor(s, o, 16);
            float m = s * (1.f / 32.f);
            float dx = vx - m, dy = vy - m;
            float qv = dx * dx + dy * dy;
#pragma unroll
            for (int o = 1; o < 16; o <<= 1) qv += __shfl_xor(qv, o, 16);
            float rs = rsqrtf(qv * (1.f / 32.f) + EPS);
            float y0 = dx * rs * g2[2 * l] + be2[2 * l];
            float y1 = dy * rs * g2[2 * l + 1] + be2[2 * l + 1];
            ys[tl][2 * l]     = (f16)(y0 > 0.f ? y0 : 0.f);
            ys[tl][2 * l + 1] = (f16)(y1 > 0.f ? y1 : 0.f);
        } else {
            ys[tl][2 * l] = (f16)0.f;
            ys[tl][2 * l + 1] = (f16)0.f;
        }
    }
    __syncthreads();

    // MLP: hidden = relu(y@Wo1+bo1) via MFMA, out = hidden@Wo2 + bo2 via reduce
    if (wv < 4) {
        f16x8 a = *(const f16x8*)&ys[wv * 16 + r][q * 8];
        f32x4 acc = {};
        acc = __builtin_amdgcn_mfma_f32_16x16x32_f16(a, bo, acc, 0, 0, 0);
#pragma unroll
        for (int v = 0; v < 4; v++) {
            float h = acc[v] + b1v;
            h = h > 0.f ? h : 0.f;
            float contrib = h * w2v;
#pragma unroll
            for (int o = 1; o < 16; o <<= 1) contrib += __shfl_xor(contrib, o, 16);
            int n = nb + wv * 16 + q * 4 + v;
            if (r == 0 && n < N) out[n] = contrib + bo2[0];
        }
    }
}

extern "C" void kernel_launch(void* const* d_in, const int* in_sizes, int n_in,
                              void* d_out, int out_size, void* d_ws, size_t ws_size,
                              hipStream_t stream) {
    const float* x    = (const float*)d_in[0];
    const int*   ei   = (const int*)d_in[1];
    const float* W_in = (const float*)d_in[2];
    const float* b_in = (const float*)d_in[3];
    const float* Wl1  = (const float*)d_in[4];
    const float* bl1  = (const float*)d_in[5];
    const float* Wr1  = (const float*)d_in[6];
    const float* g1   = (const float*)d_in[7];
    const float* be1  = (const float*)d_in[8];
    const float* Wl2  = (const float*)d_in[9];
    const float* bl2  = (const float*)d_in[10];
    const float* Wr2  = (const float*)d_in[11];
    const float* g2   = (const float*)d_in[12];
    const float* be2  = (const float*)d_in[13];
    const float* Wo1  = (const float*)d_in[14];
    const float* bo1  = (const float*)d_in[15];
    const float* Wo2  = (const float*)d_in[16];
    const float* bo2  = (const float*)d_in[17];
    float* out = (float*)d_out;

    const int N = NN, E = NE;
    const int* src = ei;
    const int* tgt = ei + E;

    // workspace layout
    char* w = (char*)d_ws;
    int* wcur = (int*)w;  w += (size_t)NW * 4;
    w = (char*)(((uintptr_t)w + 15) & ~(uintptr_t)15);
    int* colw = (int*)w;  w += (size_t)NW * CAP * 4;     // 8.0 MB, CAP-strided
    f16* p1h  = (f16*)w;  w += (size_t)N * 64 * 2;
    f16* r1h  = (f16*)w;  w += (size_t)N * 64 * 2;
    f16* p2h  = (f16*)w;  w += (size_t)N * 32 * 2;
    f16* r2h  = (f16*)w;  w += (size_t)N * 32 * 2;
    f16* WinT = (f16*)w;  w += (size_t)128 * 104 * 2;
    f16* W2T  = (f16*)w;  w += (size_t)128 * 136 * 2;
    f16* W3T  = (f16*)w;  w += (size_t)64 * 72 * 2;
    f16* Wo1T = (f16*)w;  w += (size_t)16 * 40 * 2;

    // ---- 4-dispatch pipeline ----
    k_prep_init<<<PREPB, 256, 0, stream>>>(W_in, Wl1, Wr1, Wl2, Wr2, Wo1,
                                           WinT, W2T, W3T, Wo1T, wcur);
    k_wfill_inproj<<<WFB + INPB, 256, 0, stream>>>(src, tgt, wcur, colw,
                                                   x, WinT, b_in, W2T, bl1, p1h, r1h, N);
    k_agg1_proj2<<<NW, 512, 0, stream>>>((const __half2*)p1h, (const __half2*)r1h,
                                         wcur, colw, g1, be1, W3T, bl2, p2h, r2h, N);
    k_agg2_out<<<NW, 512, 0, stream>>>((const __half2*)p2h, (const __half2*)r2h,
                                       wcur, colw, g2, be2, Wo1T, bo1, Wo2, bo2, out, N);
}